// Round 11
// baseline (457.077 us; speedup 1.0000x reference)
//
#include <hip/hip_runtime.h>
#include <stdint.h>
#include <stddef.h>

#define B_ 4
#define S_ 2048
#define D_ 1024
#define H_ 16
#define DK_ 64
#define M_ (B_*S_)
#define NEGINF (-1e30f)
#define THR_ 8.0f

#if __has_builtin(__builtin_amdgcn_exp2f)
#define EXP2F(x) __builtin_amdgcn_exp2f(x)
#else
#define EXP2F(x) exp2f(x)
#endif

typedef _Float16 f16;
typedef __attribute__((ext_vector_type(8))) _Float16 f16x8;
typedef __attribute__((ext_vector_type(4))) _Float16 f16x4;
typedef __attribute__((ext_vector_type(4))) float f32x4;

// async global->LDS, 16B per lane; LDS dest = wave-uniform base + lane*16
__device__ __forceinline__ void gload16(const void* g, void* l) {
  __builtin_amdgcn_global_load_lds(
      (const __attribute__((address_space(1))) uint32_t*)g,
      (__attribute__((address_space(3))) uint32_t*)l, 16, 0, 0);
}

// K global layout (Kh): within each 64-token block, token r stored at row
// perm(r)=((r&3)<<4)|(r>>2); within each head's 64-dk row slice, 8-f16 chunk c
// stored at c^(perm(r)&7).  V global layout (Vt[bh][dk][key]): within each
// 64-key block, chunk c stored at c^(dk&7).  Consumers stage LINEARLY via
// global_load_lds and apply the XOR on ds_read (rule: linear dest +
// pre-swizzled source + swizzle on read).

// ---------------- fused prep: src cvt | weight cvt+transpose | masks ----------------
#define NB_SRC (M_*D_/8/256)        // 4096
#define NB_WT  1024
#define NB_MSK ((S_*S_/64 + B_*S_/64)/4)  // 16416
__global__ void k_prep(const float* __restrict__ src, f16* __restrict__ Xh,
                       const float* __restrict__ W0, const float* __restrict__ W1,
                       const float* __restrict__ W2, const float* __restrict__ W3,
                       f16* __restrict__ WtBase,
                       const int* __restrict__ am, const int* __restrict__ kp,
                       uint32_t* __restrict__ amw, uint32_t* __restrict__ kpw) {
  __shared__ float tile[64][65];
  const int bid = blockIdx.x, t = threadIdx.x;
  if (bid < NB_SRC) {
    int i = bid*256 + t;
    const f32x4* p = (const f32x4*)src;
    f32x4 a = p[2*i], b = p[2*i+1];
    f16x8 o;
    o[0]=(f16)a[0]; o[1]=(f16)a[1]; o[2]=(f16)a[2]; o[3]=(f16)a[3];
    o[4]=(f16)b[0]; o[5]=(f16)b[1]; o[6]=(f16)b[2]; o[7]=(f16)b[3];
    ((f16x8*)Xh)[i] = o;
  } else if (bid < NB_SRC + NB_WT) {
    int r = bid - NB_SRC;
    int z = r >> 8, rem = r & 255;
    const float* W = (z==0)?W0:(z==1)?W1:(z==2)?W2:W3;
    f16* Wt = WtBase + (size_t)z*D_*D_;
    int k0 = (rem & 15)*64, n0 = (rem >> 4)*64;
    int c4 = t & 15, r0 = t >> 4;
    #pragma unroll
    for (int i = 0; i < 4; i++) {
      int rr = r0 + i*16;
      f32x4 v = *(const f32x4*)&W[(size_t)(k0 + rr)*D_ + n0 + c4*4];
      tile[rr][c4*4+0]=v[0]; tile[rr][c4*4+1]=v[1]; tile[rr][c4*4+2]=v[2]; tile[rr][c4*4+3]=v[3];
    }
    __syncthreads();
    #pragma unroll
    for (int i = 0; i < 4; i++) {
      int nr = r0 + i*16;
      int kc = c4*4;
      f16x4 o;
      o[0]=(f16)tile[kc+0][nr]; o[1]=(f16)tile[kc+1][nr];
      o[2]=(f16)tile[kc+2][nr]; o[3]=(f16)tile[kc+3][nr];
      *(f16x4*)&Wt[(size_t)(n0+nr)*D_ + k0 + kc] = o;
    }
  } else {
    int g = (bid - NB_SRC - NB_WT)*4 + (t>>6);
    int lane = t & 63;
    const int NAM = S_*S_/64;
    int v; uint32_t* dst;
    if (g < NAM) { v = am[(size_t)g*64 + lane]; dst = amw + (size_t)g*2; }
    else         { int g2 = g - NAM; v = kp[(size_t)g2*64 + lane]; dst = kpw + (size_t)g2*2; }
    unsigned long long bal = __ballot(v != 0);
    if (lane == 0) { dst[0] = (uint32_t)bal; dst[1] = (uint32_t)(bal>>32); }
  }
}

// ---------------- fused QKV GEMM (m97 structure), z selects projection ----------------
// z=0: Q out f16 scaled by 0.125*log2(e).  z=1: K -> permuted+swizzled Kh.
// z=2: V -> Vt[bh][dk][key] with chunk swizzle.
__global__ __launch_bounds__(256, 2) void k_gemm_qkv(
    const f16* __restrict__ A, const f16* __restrict__ WtBase,
    const float* __restrict__ bq, const float* __restrict__ bk, const float* __restrict__ bv,
    f16* __restrict__ Qh, f16* __restrict__ Kh, f16* __restrict__ VtO) {
  __shared__ f16 As[128][64];
  __shared__ f16 Bs[128][64];
  const int z = blockIdx.z;
  const f16* Wt = WtBase + (size_t)z*D_*D_;
  const float* bias = (z==0) ? bq : (z==1) ? bk : bv;
  const int t = threadIdx.x;
  const int wave = t>>6, lane = t&63;
  const int lr = lane&15, lg = lane>>4;
  const int wr = wave>>1, wc = wave&1;
  const int m0 = blockIdx.y*128, n0 = blockIdx.x*128;
  const int srow = lane>>3, scol = (lane&7)*8;

  const f16* ga = A  + (size_t)m0*D_;
  const f16* gb = Wt + (size_t)n0*D_;

  f32x4 acc[4][4] = {};
  for (int kk=0; kk<16; kk++) {
    __syncthreads();
    #pragma unroll
    for (int i=0;i<4;i++){
      int rbase = i*32 + wave*8;
      gload16(&ga[(size_t)(rbase+srow)*D_ + kk*64 + scol], &As[rbase][0]);
      gload16(&gb[(size_t)(rbase+srow)*D_ + kk*64 + scol], &Bs[rbase][0]);
    }
    __syncthreads();
    #pragma unroll
    for (int s=0;s<2;s++) {
      f16x8 af[4], bf[4];
      #pragma unroll
      for (int i=0;i<4;i++) af[i] = *(const f16x8*)&As[wr*64 + i*16 + lr][s*32 + lg*8];
      #pragma unroll
      for (int i=0;i<4;i++) bf[i] = *(const f16x8*)&Bs[wc*64 + i*16 + lr][s*32 + lg*8];
      #pragma unroll
      for (int i=0;i<4;i++)
        #pragma unroll
        for (int j=0;j<4;j++)
          acc[i][j] = __builtin_amdgcn_mfma_f32_16x16x32_f16(af[i], bf[j], acc[i][j],0,0,0);
    }
  }
  #pragma unroll
  for (int fn=0; fn<4; fn++) {
    int n = n0 + wc*64 + fn*16 + lr;
    float bvv = bias[n];
    #pragma unroll
    for (int fm=0; fm<4; fm++) {
      int mrow = m0 + wr*64 + fm*16 + lg*4;
      if (z == 0) {
        #pragma unroll
        for (int j=0;j<4;j++) Qh[(size_t)(mrow+j)*D_ + n] = (f16)((acc[fm][fn][j] + bvv)*0.1803368801111204f);
      } else if (z == 1) {
        #pragma unroll
        for (int j=0;j<4;j++) {
          int m = mrow + j;
          int rr = m & 63;
          int pr = ((rr&3)<<4) | (rr>>2);
          int mg_ = (m & ~63) | pr;
          int cp = ((n>>3)&7) ^ (pr&7);
          int n2 = (n & ~63) | (cp<<3) | (n&7);
          Kh[(size_t)mg_*D_ + n2] = (f16)(acc[fm][fn][j] + bvv);
        }
      } else {
        int hh = n >> 6, dk = n & 63;
        int bb = mrow >> 11, ss = mrow & (S_-1);
        int cp = ((ss>>3)&7) ^ (dk&7);
        int ss2 = (ss & ~56) | (cp<<3);     // keep ss&7 and 64-block bits
        f16x4 o;
        #pragma unroll
        for (int j=0;j<4;j++) o[j] = (f16)(acc[fm][fn][j] + bvv);
        *(f16x4*)&VtO[((size_t)(bb*H_ + hh)*DK_ + dk)*S_ + ss2] = o;
      }
    }
  }
}

// ---------------- output GEMM: f32 out ----------------
__global__ __launch_bounds__(256, 2) void k_gemm_o(
    const f16* __restrict__ A, const f16* __restrict__ Wt,
    const float* __restrict__ bias, float* __restrict__ O) {
  __shared__ f16 As[128][64];
  __shared__ f16 Bs[128][64];
  const int t = threadIdx.x;
  const int wave = t>>6, lane = t&63;
  const int lr = lane&15, lg = lane>>4;
  const int wr = wave>>1, wc = wave&1;
  const int m0 = blockIdx.y*128, n0 = blockIdx.x*128;
  const int srow = lane>>3, scol = (lane&7)*8;

  const f16* ga = A  + (size_t)m0*D_;
  const f16* gb = Wt + (size_t)n0*D_;

  f32x4 acc[4][4] = {};
  for (int kk=0; kk<16; kk++) {
    __syncthreads();
    #pragma unroll
    for (int i=0;i<4;i++){
      int rbase = i*32 + wave*8;
      gload16(&ga[(size_t)(rbase+srow)*D_ + kk*64 + scol], &As[rbase][0]);
      gload16(&gb[(size_t)(rbase+srow)*D_ + kk*64 + scol], &Bs[rbase][0]);
    }
    __syncthreads();
    #pragma unroll
    for (int s=0;s<2;s++) {
      f16x8 af[4], bf[4];
      #pragma unroll
      for (int i=0;i<4;i++) af[i] = *(const f16x8*)&As[wr*64 + i*16 + lr][s*32 + lg*8];
      #pragma unroll
      for (int i=0;i<4;i++) bf[i] = *(const f16x8*)&Bs[wc*64 + i*16 + lr][s*32 + lg*8];
      #pragma unroll
      for (int i=0;i<4;i++)
        #pragma unroll
        for (int j=0;j<4;j++)
          acc[i][j] = __builtin_amdgcn_mfma_f32_16x16x32_f16(af[i], bf[j], acc[i][j],0,0,0);
    }
  }
  #pragma unroll
  for (int fn=0; fn<4; fn++) {
    int n = n0 + wc*64 + fn*16 + lr;
    float bv = bias[n];
    #pragma unroll
    for (int fm=0; fm<4; fm++) {
      int mrow = m0 + wr*64 + fm*16 + lg*4;
      #pragma unroll
      for (int j=0;j<4;j++) O[(size_t)(mrow+j)*D_ + n] = acc[fm][fn][j] + bv;
    }
  }
}

// ---------------- single-pass flash: gload_lds staging + single-barrier dbuf ----------------
// K/V staged async via global_load_lds into double-buffered linear LDS (global
// layouts pre-permuted/swizzled by the producer). ONE barrier per kt: loads for
// kt+1 issue right after it; their L2 latency hides under kt's MFMA+softmax;
// the compiler's per-wave vmcnt(0) drain before the next barrier completes them.
__global__ __launch_bounds__(256, 2) void k_flash(
    const f16* __restrict__ Qh, const f16* __restrict__ Kh, const f16* __restrict__ Vt,
    const uint32_t* __restrict__ amw, const uint32_t* __restrict__ kpw,
    float2* __restrict__ stats, f16* __restrict__ ctx) {
  __shared__ f16 Kt[2][64][64];
  __shared__ f16 Vtt[2][64][64];
  __shared__ f16 Pl[4][32][72];
  __shared__ float ssc[4][2][16];

  const int t = threadIdx.x, wave = t>>6, lane = t&63;
  const int lr = lane&15, lg = lane>>4;
  const int sh4 = 4*lr;
  const int flat = blockIdx.x;
  const int vid = (flat & 7)*128 + (flat >> 3);   // XCD swizzle: 8 bh per XCD
  const int bh = vid >> 4, qt = vid & 15;
  const int b = bh >> 4, h = bh & 15;
  const int qb = qt*128 + wave*32;

  const f16* kbase = Kh + (size_t)b*S_*D_ + h*64;
  const f16* vbase = Vt + (size_t)bh*DK_*S_;
  const int srow = t>>3, sch = (t&7)*8;   // staging: row slot, 16B chunk
  const int w8 = wave*8;                   // wave-uniform LDS row base
  const int ch0 = ((0|lg) ^ (lr&7))*8;     // read-side chunk XOR, s=0
  const int ch1 = ((4|lg) ^ (lr&7))*8;     // s=1

  f16x8 qf[2][2];
  #pragma unroll
  for (int qi=0; qi<2; qi++)
    #pragma unroll
    for (int s=0; s<2; s++)
      qf[qi][s] = *(const f16x8*)&Qh[(size_t)(b*S_ + qb + qi*16 + lr)*D_ + h*64 + s*32 + lg*8];

  float mu[2][4], mg[2][4], l_[2][4];
  #pragma unroll
  for (int qi=0;qi<2;qi++)
    #pragma unroll
    for (int j=0;j<4;j++){ mu[qi][j]=NEGINF; mg[qi][j]=0.f; l_[qi][j]=0.f; }
  f32x4 ct[4][2] = {};

  // prologue: stage kt=0 into buffer 0
  gload16(&kbase[(size_t)srow*D_ + sch],        &Kt[0][w8][0]);
  gload16(&kbase[(size_t)(32+srow)*D_ + sch],   &Kt[0][32+w8][0]);
  gload16(&vbase[(size_t)srow*S_ + sch],        &Vtt[0][w8][0]);
  gload16(&vbase[(size_t)(32+srow)*S_ + sch],   &Vtt[0][32+w8][0]);

  int cur = 0;
  for (int kt=0; kt<32; kt++) {
    __syncthreads();   // buf[cur] ready (per-wave vmcnt drained before barrier)
    if (kt < 31) {     // issue next tile into buf^1; latency hides under compute
      int nxt = cur^1, k64 = (kt+1)*64;
      gload16(&kbase[(size_t)(k64+srow)*D_ + sch],      &Kt[nxt][w8][0]);
      gload16(&kbase[(size_t)(k64+32+srow)*D_ + sch],   &Kt[nxt][32+w8][0]);
      gload16(&vbase[(size_t)srow*S_ + k64 + sch],      &Vtt[nxt][w8][0]);
      gload16(&vbase[(size_t)(32+srow)*S_ + k64 + sch], &Vtt[nxt][32+w8][0]);
    }
    f32x4 sf[2][4] = {};
    #pragma unroll
    for (int s=0;s<2;s++) {
      const int chs = s ? ch1 : ch0;
      #pragma unroll
      for (int f=0;f<4;f++) {
        f16x8 kf = *(const f16x8*)&Kt[cur][f*16 + lr][chs];
        #pragma unroll
        for (int qi=0;qi<2;qi++)
          sf[qi][f] = __builtin_amdgcn_mfma_f32_16x16x32_f16(qf[qi][s], kf, sf[qi][f],0,0,0);
      }
    }
    uint32_t kw0 = kpw[b*64 + kt*2], kw1 = kpw[b*64 + kt*2 + 1];
    int nib[2][4]; float tmx[2][4]; int need = 0;
    #pragma unroll
    for (int qi=0;qi<2;qi++)
      #pragma unroll
      for (int j=0;j<4;j++) {
        int qrow = qb + qi*16 + lg*4 + j;
        uint32_t a0 = amw[(size_t)qrow*64 + kt*2]     | kw0;
        uint32_t a1 = amw[(size_t)qrow*64 + kt*2 + 1] | kw1;
        int nb = (int)((((uint64_t)a1<<32) | a0) >> sh4) & 15;
        nib[qi][j] = nb;
        float x0 = (nb&1) ? NEGINF : sf[qi][0][j];
        float x1 = (nb&2) ? NEGINF : sf[qi][1][j];
        float x2 = (nb&4) ? NEGINF : sf[qi][2][j];
        float x3 = (nb&8) ? NEGINF : sf[qi][3][j];
        float tm = fmaxf(fmaxf(x0,x1), fmaxf(x2,x3));
        tmx[qi][j] = tm;
        need |= (tm > mu[qi][j] + THR_) ? 1 : 0;
      }
    if (__any(need)) {   // rare wave-uniform rescale
      #pragma unroll
      for (int qi=0;qi<2;qi++)
        #pragma unroll
        for (int j=0;j<4;j++) {
          float gm = tmx[qi][j];
          #pragma unroll
          for (int d=1; d<16; d<<=1) gm = fmaxf(gm, __shfl_xor(gm, d));
          float mnew = fmaxf(mu[qi][j], gm);
          float mgn = (mnew <= NEGINF) ? 0.f : mnew;
          float sc = EXP2F(mg[qi][j] - mgn);
          l_[qi][j] *= sc;
          mu[qi][j] = mnew; mg[qi][j] = mgn;
          if (lr == 0) ssc[wave][qi][lg*4+j] = sc;
        }
      asm volatile("s_waitcnt lgkmcnt(0)" ::: "memory");
      __builtin_amdgcn_sched_barrier(0);
      float sv_0 = ssc[wave][0][lr], sv_1 = ssc[wave][1][lr];
      #pragma unroll
      for (int mf=0; mf<4; mf++)
        #pragma unroll
        for (int c=0;c<4;c++) { ct[mf][0][c] *= sv_0; ct[mf][1][c] *= sv_1; }
    }
    #pragma unroll
    for (int qi=0;qi<2;qi++)
      #pragma unroll
      for (int j=0;j<4;j++) {
        int nb = nib[qi][j];
        float x0 = (nb&1) ? NEGINF : sf[qi][0][j];
        float x1 = (nb&2) ? NEGINF : sf[qi][1][j];
        float x2 = (nb&4) ? NEGINF : sf[qi][2][j];
        float x3 = (nb&8) ? NEGINF : sf[qi][3][j];
        float e0 = EXP2F(x0 - mg[qi][j]);
        float e1 = EXP2F(x1 - mg[qi][j]);
        float e2 = EXP2F(x2 - mg[qi][j]);
        float e3 = EXP2F(x3 - mg[qi][j]);
        l_[qi][j] += (e0+e1)+(e2+e3);
        f16x4 pv4; pv4[0]=(f16)e0; pv4[1]=(f16)e1; pv4[2]=(f16)e2; pv4[3]=(f16)e3;
        *(f16x4*)&Pl[wave][qi*16 + lg*4 + j][sh4] = pv4;
      }
    #pragma unroll
    for (int s=0;s<2;s++) {
      const int chs = s ? ch1 : ch0;
      f16x8 pb0 = *(const f16x8*)&Pl[wave][lr][s*32 + lg*8];
      f16x8 pb1 = *(const f16x8*)&Pl[wave][16 + lr][s*32 + lg*8];
      #pragma unroll
      for (int mf=0; mf<4; mf++) {
        f16x8 va = *(const f16x8*)&Vtt[cur][mf*16 + lr][chs];
        ct[mf][0] = __builtin_amdgcn_mfma_f32_16x16x32_f16(va, pb0, ct[mf][0],0,0,0);
        ct[mf][1] = __builtin_amdgcn_mfma_f32_16x16x32_f16(va, pb1, ct[mf][1],0,0,0);
      }
    }
    cur ^= 1;
  }

  // merge per-lane l across the 16-lane group; publish stats; normalize context
  #pragma unroll
  for (int qi=0;qi<2;qi++)
    #pragma unroll
    for (int j=0;j<4;j++) {
      float ls = l_[qi][j];
      #pragma unroll
      for (int d=1; d<16; d<<=1) ls += __shfl_xor(ls, d);
      float ilv = (ls > 0.f) ? 1.f/ls : 0.f;
      if (lr == 0) {
        ssc[wave][qi][lg*4+j] = ilv;
        stats[(size_t)bh*S_ + qb + qi*16 + lg*4 + j] = make_float2(mg[qi][j], ilv);
      }
    }
  asm volatile("s_waitcnt lgkmcnt(0)" ::: "memory");
  __builtin_amdgcn_sched_barrier(0);
  float il0 = ssc[wave][0][lr], il1 = ssc[wave][1][lr];

  // ct[mf][qi]: row dk = mf*16+lg*4+j, col q = qi*16+lr  ->  bounce to [q][dk]
  #pragma unroll
  for (int mf=0; mf<4; mf++)
    #pragma unroll
    for (int qi=0; qi<2; qi++) {
      float ilc = qi ? il1 : il0;
      f16x4 o;
      #pragma unroll
      for (int j=0;j<4;j++) o[j] = (f16)(ct[mf][qi][j] * ilc);
      *(f16x4*)&Pl[wave][qi*16 + lr][mf*16 + lg*4] = o;
    }
  __builtin_amdgcn_s_waitcnt(0);
  #pragma unroll
  for (int i=0;i<4;i++) {
    int idx = i*64 + lane;
    int row = idx >> 3, ch = idx & 7;
    f16x8 o = *(const f16x8*)&Pl[wave][row][ch*8];
    *(f16x8*)&ctx[(size_t)(b*S_ + qb + row)*D_ + h*64 + ch*8] = o;
  }
}

// ---------------- attn writer: one-shot 128x128 tile, gload_lds K staging, NT stores ----------------
__global__ __launch_bounds__(256, 2) void k_attnw(
    const f16* __restrict__ Qh, const f16* __restrict__ Kh,
    const uint32_t* __restrict__ amw, const uint32_t* __restrict__ kpw,
    const float2* __restrict__ stats, float* __restrict__ attnp) {
  __shared__ f16 Ks[128][64];   // linear; global already permuted+swizzled
  const int t = threadIdx.x, wave = t>>6, lane = t&63;
  const int lr = lane&15, lg = lane>>4;
  const int sh4 = 4*lr;
  const int ktb = blockIdx.x, qt = blockIdx.y, bh = blockIdx.z;
  const int b = bh >> 4, h = bh & 15;
  const int qb = qt*128, kb = ktb*128;
  const int srow = t>>3, sch = (t&7)*8, w8 = wave*8;
  const int ch0 = ((0|lg) ^ (lr&7))*8;
  const int ch1 = ((4|lg) ^ (lr&7))*8;

  #pragma unroll
  for (int q2=0; q2<4; q2++)
    gload16(&Kh[(size_t)(b*S_ + kb + q2*32 + srow)*D_ + h*64 + sch], &Ks[q2*32 + w8][0]);

  f16x8 qf[2][2];
  #pragma unroll
  for (int qi=0; qi<2; qi++)
    #pragma unroll
    for (int s=0; s<2; s++)
      qf[qi][s] = *(const f16x8*)&Qh[(size_t)(b*S_ + qb + wave*32 + qi*16 + lr)*D_ + h*64 + s*32 + lg*8];
  __syncthreads();   // only barrier; drains gload_lds

  f32x4 sf[2][8] = {};
  #pragma unroll
  for (int s=0;s<2;s++) {
    const int chs = s ? ch1 : ch0;
    #pragma unroll
    for (int f=0;f<8;f++) {
      f16x8 kf = *(const f16x8*)&Ks[f*16 + lr][chs];
      #pragma unroll
      for (int qi=0;qi<2;qi++)
        sf[qi][f] = __builtin_amdgcn_mfma_f32_16x16x32_f16(qf[qi][s], kf, sf[qi][f],0,0,0);
    }
  }

  uint32_t kw[4];
  #pragma unroll
  for (int i=0;i<4;i++) kw[i] = kpw[b*64 + ktb*4 + i];

  #pragma unroll
  for (int qi=0;qi<2;qi++)
    #pragma unroll
    for (int j=0;j<4;j++) {
      int qrow = qb + wave*32 + qi*16 + lg*4 + j;
      float2 st = stats[(size_t)bh*S_ + qrow];
      #pragma unroll
      for (int half=0; half<2; half++) {
        uint32_t a0 = amw[(size_t)qrow*64 + ktb*4 + half*2]     | kw[half*2];
        uint32_t a1 = amw[(size_t)qrow*64 + ktb*4 + half*2 + 1] | kw[half*2+1];
        int nb = (int)((((uint64_t)a1<<32) | a0) >> sh4) & 15;
        float x0 = (nb&1) ? NEGINF : sf[qi][half*4+0][j];
        float x1 = (nb&2) ? NEGINF : sf[qi][half*4+1][j];
        float x2 = (nb&4) ? NEGINF : sf[qi][half*4+2][j];
        float x3 = (nb&8) ? NEGINF : sf[qi][half*4+3][j];
        f32x4 ev;
        ev[0] = EXP2F(x0 - st.x) * st.y;
        ev[1] = EXP2F(x1 - st.x) * st.y;
        ev[2] = EXP2F(x2 - st.x) * st.y;
        ev[3] = EXP2F(x3 - st.x) * st.y;
        __builtin_nontemporal_store(ev,
            (f32x4*)&attnp[((size_t)bh*S_ + qrow)*S_ + kb + half*64 + sh4]);
      }
    }
}

// ---------------- launch ----------------
extern "C" void kernel_launch(void* const* d_in, const int* in_sizes, int n_in,
                              void* d_out, int out_size, void* d_ws, size_t ws_size,
                              hipStream_t stream) {
  const float* src = (const float*)d_in[0];
  const int*   am  = (const int*)d_in[1];
  const int*   kp  = (const int*)d_in[2];
  const float* Wq  = (const float*)d_in[3];
  const float* bq  = (const float*)d_in[4];
  const float* Wk  = (const float*)d_in[5];
  const float* bk  = (const float*)d_in[6];
  const float* Wv  = (const float*)d_in[7];
  const float* bv  = (const float*)d_in[8];
  const float* Wo  = (const float*)d_in[9];
  const float* bo  = (const float*)d_in[10];

  const size_t need = (size_t)M_*D_*2        // Xh
                    + (size_t)4*D_*D_*2      // Wth
                    + (size_t)4*M_*D_*2      // Qh,Kh,Vt,CT
                    + (size_t)S_*S_/8        // amw
                    + (size_t)B_*S_/8        // kpw
                    + (size_t)M_*8;          // stats
  if (ws_size < need) return;

  char* w = (char*)d_ws;
  f16* Xh  = (f16*)w;  w += (size_t)M_*D_*2;
  f16* Wth = (f16*)w;  w += (size_t)4*D_*D_*2;
  f16* Qh  = (f16*)w;  w += (size_t)M_*D_*2;
  f16* Kh  = (f16*)w;  w += (size_t)M_*D_*2;
  f16* Vt  = (f16*)w;  w += (size_t)M_*D_*2;
  f16* CT  = (f16*)w;  w += (size_t)M_*D_*2;
  uint32_t* amw = (uint32_t*)w; w += (size_t)S_*S_/8;
  uint32_t* kpw = (uint32_t*)w; w += (size_t)B_*S_/8;
  float2* stats = (float2*)w;

  float* outp  = (float*)d_out;
  float* attnp = outp + (size_t)M_*D_;

  k_prep<<<NB_SRC + NB_WT + NB_MSK, 256, 0, stream>>>(
      src, Xh, Wq, Wk, Wv, Wo, Wth, am, kp, amw, kpw);
  k_gemm_qkv<<<dim3(8,64,3), 256, 0, stream>>>(Xh, Wth, bq, bk, bv, Qh, Kh, Vt);
  k_flash<<<1024, 256, 0, stream>>>(Qh, Kh, Vt, amw, kpw, stats, CT);
  k_gemm_o<<<dim3(8,64), 256, 0, stream>>>(CT, Wth + 3*(size_t)D_*D_, bo, outp);
  k_attnw<<<dim3(16,16,64), 256, 0, stream>>>(Qh, Kh, amw, kpw, stats, attnp);
}

// Round 12
// 449.058 us; speedup vs baseline: 1.0179x; 1.0179x over previous
//
#include <hip/hip_runtime.h>
#include <stdint.h>
#include <stddef.h>

#define B_ 4
#define S_ 2048
#define D_ 1024
#define H_ 16
#define DK_ 64
#define M_ (B_*S_)
#define NEGINF (-1e30f)
#define THR_ 8.0f

#if __has_builtin(__builtin_amdgcn_exp2f)
#define EXP2F(x) __builtin_amdgcn_exp2f(x)
#else
#define EXP2F(x) exp2f(x)
#endif

typedef _Float16 f16;
typedef __attribute__((ext_vector_type(8))) _Float16 f16x8;
typedef __attribute__((ext_vector_type(4))) _Float16 f16x4;
typedef __attribute__((ext_vector_type(4))) float f32x4;

// async global->LDS, 16B per lane; LDS dest = wave-uniform base + lane*16
__device__ __forceinline__ void gload16(const void* g, void* l) {
  __builtin_amdgcn_global_load_lds(
      (const __attribute__((address_space(1))) uint32_t*)g,
      (__attribute__((address_space(3))) uint32_t*)l, 16, 0, 0);
}

// K global layout (Kh): within each 64-token block, token r stored at row
// perm(r)=((r&3)<<4)|(r>>2); within each head's 64-dk row slice, 8-f16 chunk c
// stored at c^(perm(r)&7).  V global layout (Vt[bh][dk][key]): within each
// 64-key block, chunk c stored at c^(dk&7).  Consumers stage LINEARLY via
// global_load_lds and apply the XOR on ds_read.

// ---------------- fused prep: src cvt | weight cvt+transpose | masks ----------------
#define NB_SRC (M_*D_/8/256)        // 4096
#define NB_WT  1024
#define NB_MSK ((S_*S_/64 + B_*S_/64)/4)  // 16416
__global__ void k_prep(const float* __restrict__ src, f16* __restrict__ Xh,
                       const float* __restrict__ W0, const float* __restrict__ W1,
                       const float* __restrict__ W2, const float* __restrict__ W3,
                       f16* __restrict__ WtBase,
                       const int* __restrict__ am, const int* __restrict__ kp,
                       uint32_t* __restrict__ amw, uint32_t* __restrict__ kpw) {
  __shared__ float tile[64][65];
  const int bid = blockIdx.x, t = threadIdx.x;
  if (bid < NB_SRC) {
    int i = bid*256 + t;
    const f32x4* p = (const f32x4*)src;
    f32x4 a = p[2*i], b = p[2*i+1];
    f16x8 o;
    o[0]=(f16)a[0]; o[1]=(f16)a[1]; o[2]=(f16)a[2]; o[3]=(f16)a[3];
    o[4]=(f16)b[0]; o[5]=(f16)b[1]; o[6]=(f16)b[2]; o[7]=(f16)b[3];
    ((f16x8*)Xh)[i] = o;
  } else if (bid < NB_SRC + NB_WT) {
    int r = bid - NB_SRC;
    int z = r >> 8, rem = r & 255;
    const float* W = (z==0)?W0:(z==1)?W1:(z==2)?W2:W3;
    f16* Wt = WtBase + (size_t)z*D_*D_;
    int k0 = (rem & 15)*64, n0 = (rem >> 4)*64;
    int c4 = t & 15, r0 = t >> 4;
    #pragma unroll
    for (int i = 0; i < 4; i++) {
      int rr = r0 + i*16;
      f32x4 v = *(const f32x4*)&W[(size_t)(k0 + rr)*D_ + n0 + c4*4];
      tile[rr][c4*4+0]=v[0]; tile[rr][c4*4+1]=v[1]; tile[rr][c4*4+2]=v[2]; tile[rr][c4*4+3]=v[3];
    }
    __syncthreads();
    #pragma unroll
    for (int i = 0; i < 4; i++) {
      int nr = r0 + i*16;
      int kc = c4*4;
      f16x4 o;
      o[0]=(f16)tile[kc+0][nr]; o[1]=(f16)tile[kc+1][nr];
      o[2]=(f16)tile[kc+2][nr]; o[3]=(f16)tile[kc+3][nr];
      *(f16x4*)&Wt[(size_t)(n0+nr)*D_ + k0 + kc] = o;
    }
  } else {
    int g = (bid - NB_SRC - NB_WT)*4 + (t>>6);
    int lane = t & 63;
    const int NAM = S_*S_/64;
    int v; uint32_t* dst;
    if (g < NAM) { v = am[(size_t)g*64 + lane]; dst = amw + (size_t)g*2; }
    else         { int g2 = g - NAM; v = kp[(size_t)g2*64 + lane]; dst = kpw + (size_t)g2*2; }
    unsigned long long bal = __ballot(v != 0);
    if (lane == 0) { dst[0] = (uint32_t)bal; dst[1] = (uint32_t)(bal>>32); }
  }
}

// ---------------- fused QKV GEMM (m97 structure), z selects projection ----------------
// z=0: Q out f16 scaled by 0.125*log2(e).  z=1: K -> permuted+swizzled Kh.
// z=2: V -> Vt[bh][dk][key] with chunk swizzle.
__global__ __launch_bounds__(256, 2) void k_gemm_qkv(
    const f16* __restrict__ A, const f16* __restrict__ WtBase,
    const float* __restrict__ bq, const float* __restrict__ bk, const float* __restrict__ bv,
    f16* __restrict__ Qh, f16* __restrict__ Kh, f16* __restrict__ VtO) {
  __shared__ f16 As[128][64];
  __shared__ f16 Bs[128][64];
  const int z = blockIdx.z;
  const f16* Wt = WtBase + (size_t)z*D_*D_;
  const float* bias = (z==0) ? bq : (z==1) ? bk : bv;
  const int t = threadIdx.x;
  const int wave = t>>6, lane = t&63;
  const int lr = lane&15, lg = lane>>4;
  const int wr = wave>>1, wc = wave&1;
  const int m0 = blockIdx.y*128, n0 = blockIdx.x*128;
  const int srow = lane>>3, scol = (lane&7)*8;

  const f16* ga = A  + (size_t)m0*D_;
  const f16* gb = Wt + (size_t)n0*D_;

  f32x4 acc[4][4] = {};
  for (int kk=0; kk<16; kk++) {
    __syncthreads();
    #pragma unroll
    for (int i=0;i<4;i++){
      int rbase = i*32 + wave*8;
      gload16(&ga[(size_t)(rbase+srow)*D_ + kk*64 + scol], &As[rbase][0]);
      gload16(&gb[(size_t)(rbase+srow)*D_ + kk*64 + scol], &Bs[rbase][0]);
    }
    __syncthreads();
    #pragma unroll
    for (int s=0;s<2;s++) {
      f16x8 af[4], bf[4];
      #pragma unroll
      for (int i=0;i<4;i++) af[i] = *(const f16x8*)&As[wr*64 + i*16 + lr][s*32 + lg*8];
      #pragma unroll
      for (int i=0;i<4;i++) bf[i] = *(const f16x8*)&Bs[wc*64 + i*16 + lr][s*32 + lg*8];
      #pragma unroll
      for (int i=0;i<4;i++)
        #pragma unroll
        for (int j=0;j<4;j++)
          acc[i][j] = __builtin_amdgcn_mfma_f32_16x16x32_f16(af[i], bf[j], acc[i][j],0,0,0);
    }
  }
  #pragma unroll
  for (int fn=0; fn<4; fn++) {
    int n = n0 + wc*64 + fn*16 + lr;
    float bvv = bias[n];
    #pragma unroll
    for (int fm=0; fm<4; fm++) {
      int mrow = m0 + wr*64 + fm*16 + lg*4;
      if (z == 0) {
        #pragma unroll
        for (int j=0;j<4;j++) Qh[(size_t)(mrow+j)*D_ + n] = (f16)((acc[fm][fn][j] + bvv)*0.1803368801111204f);
      } else if (z == 1) {
        #pragma unroll
        for (int j=0;j<4;j++) {
          int m = mrow + j;
          int rr = m & 63;
          int pr = ((rr&3)<<4) | (rr>>2);
          int mg_ = (m & ~63) | pr;
          int cp = ((n>>3)&7) ^ (pr&7);
          int n2 = (n & ~63) | (cp<<3) | (n&7);
          Kh[(size_t)mg_*D_ + n2] = (f16)(acc[fm][fn][j] + bvv);
        }
      } else {
        int hh = n >> 6, dk = n & 63;
        int bb = mrow >> 11, ss = mrow & (S_-1);
        int cp = ((ss>>3)&7) ^ (dk&7);
        int ss2 = (ss & ~56) | (cp<<3);     // keep ss&7 and 64-block bits
        f16x4 o;
        #pragma unroll
        for (int j=0;j<4;j++) o[j] = (f16)(acc[fm][fn][j] + bvv);
        *(f16x4*)&VtO[((size_t)(bb*H_ + hh)*DK_ + dk)*S_ + ss2] = o;
      }
    }
  }
}

// ---------------- output GEMM: f32 out ----------------
__global__ __launch_bounds__(256, 2) void k_gemm_o(
    const f16* __restrict__ A, const f16* __restrict__ Wt,
    const float* __restrict__ bias, float* __restrict__ O) {
  __shared__ f16 As[128][64];
  __shared__ f16 Bs[128][64];
  const int t = threadIdx.x;
  const int wave = t>>6, lane = t&63;
  const int lr = lane&15, lg = lane>>4;
  const int wr = wave>>1, wc = wave&1;
  const int m0 = blockIdx.y*128, n0 = blockIdx.x*128;
  const int srow = lane>>3, scol = (lane&7)*8;

  const f16* ga = A  + (size_t)m0*D_;
  const f16* gb = Wt + (size_t)n0*D_;

  f32x4 acc[4][4] = {};
  for (int kk=0; kk<16; kk++) {
    __syncthreads();
    #pragma unroll
    for (int i=0;i<4;i++){
      int rbase = i*32 + wave*8;
      gload16(&ga[(size_t)(rbase+srow)*D_ + kk*64 + scol], &As[rbase][0]);
      gload16(&gb[(size_t)(rbase+srow)*D_ + kk*64 + scol], &Bs[rbase][0]);
    }
    __syncthreads();
    #pragma unroll
    for (int s=0;s<2;s++) {
      f16x8 af[4], bf[4];
      #pragma unroll
      for (int i=0;i<4;i++) af[i] = *(const f16x8*)&As[wr*64 + i*16 + lr][s*32 + lg*8];
      #pragma unroll
      for (int i=0;i<4;i++) bf[i] = *(const f16x8*)&Bs[wc*64 + i*16 + lr][s*32 + lg*8];
      #pragma unroll
      for (int i=0;i<4;i++)
        #pragma unroll
        for (int j=0;j<4;j++)
          acc[i][j] = __builtin_amdgcn_mfma_f32_16x16x32_f16(af[i], bf[j], acc[i][j],0,0,0);
    }
  }
  #pragma unroll
  for (int fn=0; fn<4; fn++) {
    int n = n0 + wc*64 + fn*16 + lr;
    float bv = bias[n];
    #pragma unroll
    for (int fm=0; fm<4; fm++) {
      int mrow = m0 + wr*64 + fm*16 + lg*4;
      #pragma unroll
      for (int j=0;j<4;j++) O[(size_t)(mrow+j)*D_ + n] = acc[fm][fn][j] + bv;
    }
  }
}

// ---------------- single-pass flash: 64 q-rows/wave (qi=4) ----------------
// Each kf/va LDS fragment read now feeds 4 MFMAs (was 2): LDS-pipe cost per
// MFMA drops ~36%. 256 q-rows/block, grid 512 = 2 blocks/CU, single batch.
// K/V staged async (gload_lds) into double-buffered linear LDS from
// pre-permuted/swizzled global; ONE barrier per kt.
__global__ __launch_bounds__(256, 2) void k_flash(
    const f16* __restrict__ Qh, const f16* __restrict__ Kh, const f16* __restrict__ Vt,
    const uint32_t* __restrict__ amw, const uint32_t* __restrict__ kpw,
    float2* __restrict__ stats, f16* __restrict__ ctx) {
  __shared__ f16 Kt[2][64][64];
  __shared__ f16 Vtt[2][64][64];
  __shared__ f16 Pl[4][64][72];
  __shared__ float ssc[4][4][16];

  const int t = threadIdx.x, wave = t>>6, lane = t&63;
  const int lr = lane&15, lg = lane>>4;
  const int sh4 = 4*lr;
  const int flat = blockIdx.x;
  const int vid = (flat & 7)*64 + (flat >> 3);   // XCD swizzle: 64 vids per XCD
  const int bh = vid >> 3, qt = vid & 7;
  const int b = bh >> 4, h = bh & 15;
  const int qb = qt*256 + wave*64;               // this wave's 64 q rows

  const f16* kbase = Kh + (size_t)b*S_*D_ + h*64;
  const f16* vbase = Vt + (size_t)bh*DK_*S_;
  const int srow = t>>3, sch = (t&7)*8;   // staging: row slot, 16B chunk
  const int w8 = wave*8;                   // wave-uniform LDS row base
  const int ch0 = ((0|lg) ^ (lr&7))*8;     // read-side chunk XOR, s=0
  const int ch1 = ((4|lg) ^ (lr&7))*8;     // s=1

  f16x8 qf[4][2];
  #pragma unroll
  for (int qi=0; qi<4; qi++)
    #pragma unroll
    for (int s=0; s<2; s++)
      qf[qi][s] = *(const f16x8*)&Qh[(size_t)(b*S_ + qb + qi*16 + lr)*D_ + h*64 + s*32 + lg*8];

  float mu[4][4], l_[4][4];
  #pragma unroll
  for (int qi=0;qi<4;qi++)
    #pragma unroll
    for (int j=0;j<4;j++){ mu[qi][j]=NEGINF; l_[qi][j]=0.f; }
  f32x4 ct[4][4] = {};

  // prologue: stage kt=0 into buffer 0
  gload16(&kbase[(size_t)srow*D_ + sch],        &Kt[0][w8][0]);
  gload16(&kbase[(size_t)(32+srow)*D_ + sch],   &Kt[0][32+w8][0]);
  gload16(&vbase[(size_t)srow*S_ + sch],        &Vtt[0][w8][0]);
  gload16(&vbase[(size_t)(32+srow)*S_ + sch],   &Vtt[0][32+w8][0]);

  int cur = 0;
  for (int kt=0; kt<32; kt++) {
    __syncthreads();   // buf[cur] ready
    if (kt < 31) {     // issue next tile into buf^1; latency hides under compute
      int nxt = cur^1, k64 = (kt+1)*64;
      gload16(&kbase[(size_t)(k64+srow)*D_ + sch],      &Kt[nxt][w8][0]);
      gload16(&kbase[(size_t)(k64+32+srow)*D_ + sch],   &Kt[nxt][32+w8][0]);
      gload16(&vbase[(size_t)srow*S_ + k64 + sch],      &Vtt[nxt][w8][0]);
      gload16(&vbase[(size_t)(32+srow)*S_ + k64 + sch], &Vtt[nxt][32+w8][0]);
    }
    // QK^T: each kf read feeds 4 MFMAs
    f32x4 sf[4][4] = {};
    #pragma unroll
    for (int s=0;s<2;s++) {
      const int chs = s ? ch1 : ch0;
      #pragma unroll
      for (int f=0;f<4;f++) {
        f16x8 kf = *(const f16x8*)&Kt[cur][f*16 + lr][chs];
        #pragma unroll
        for (int qi=0;qi<4;qi++)
          sf[qi][f] = __builtin_amdgcn_mfma_f32_16x16x32_f16(qf[qi][s], kf, sf[qi][f],0,0,0);
      }
    }
    uint32_t kw0 = kpw[b*64 + kt*2], kw1 = kpw[b*64 + kt*2 + 1];
    #pragma unroll
    for (int qi=0;qi<4;qi++) {
      float tmq[4];
      #pragma unroll
      for (int j=0;j<4;j++) {
        int qrow = qb + qi*16 + lg*4 + j;
        uint32_t a0 = amw[(size_t)qrow*64 + kt*2]     | kw0;
        uint32_t a1 = amw[(size_t)qrow*64 + kt*2 + 1] | kw1;
        int nb = (int)((((uint64_t)a1<<32) | a0) >> sh4) & 15;
        sf[qi][0][j] = (nb&1) ? NEGINF : sf[qi][0][j];
        sf[qi][1][j] = (nb&2) ? NEGINF : sf[qi][1][j];
        sf[qi][2][j] = (nb&4) ? NEGINF : sf[qi][2][j];
        sf[qi][3][j] = (nb&8) ? NEGINF : sf[qi][3][j];
        tmq[j] = fmaxf(fmaxf(sf[qi][0][j], sf[qi][1][j]),
                       fmaxf(sf[qi][2][j], sf[qi][3][j]));
      }
      int need = 0;
      #pragma unroll
      for (int j=0;j<4;j++) need |= (tmq[j] > mu[qi][j] + THR_) ? 1 : 0;
      if (__any(need)) {   // rare per-qi rescale
        #pragma unroll
        for (int j=0;j<4;j++) {
          float gm = tmq[j];
          #pragma unroll
          for (int d=1; d<16; d<<=1) gm = fmaxf(gm, __shfl_xor(gm, d));
          float mnew = fmaxf(mu[qi][j], gm);
          float mgo = (mu[qi][j] <= NEGINF) ? 0.f : mu[qi][j];
          float mgn = (mnew <= NEGINF) ? 0.f : mnew;
          float sc = EXP2F(mgo - mgn);
          l_[qi][j] *= sc;
          mu[qi][j] = mnew;
          if (lr == 0) ssc[wave][qi][lg*4+j] = sc;
        }
        asm volatile("s_waitcnt lgkmcnt(0)" ::: "memory");
        __builtin_amdgcn_sched_barrier(0);
        float svv = ssc[wave][qi][lr];
        #pragma unroll
        for (int mf=0; mf<4; mf++)
          #pragma unroll
          for (int c=0;c<4;c++) ct[mf][qi][c] *= svv;
      }
      #pragma unroll
      for (int j=0;j<4;j++) {
        float mgv = (mu[qi][j] <= NEGINF) ? 0.f : mu[qi][j];
        float e0 = EXP2F(sf[qi][0][j] - mgv);
        float e1 = EXP2F(sf[qi][1][j] - mgv);
        float e2 = EXP2F(sf[qi][2][j] - mgv);
        float e3 = EXP2F(sf[qi][3][j] - mgv);
        l_[qi][j] += (e0+e1)+(e2+e3);
        f16x4 pv4; pv4[0]=(f16)e0; pv4[1]=(f16)e1; pv4[2]=(f16)e2; pv4[3]=(f16)e3;
        *(f16x4*)&Pl[wave][qi*16 + lg*4 + j][sh4] = pv4;
      }
    }
    // PV: each va read feeds 4 MFMAs
    #pragma unroll
    for (int s=0;s<2;s++) {
      const int chs = s ? ch1 : ch0;
      f16x8 pb[4];
      #pragma unroll
      for (int qi=0;qi<4;qi++)
        pb[qi] = *(const f16x8*)&Pl[wave][qi*16 + lr][s*32 + lg*8];
      #pragma unroll
      for (int mf=0; mf<4; mf++) {
        f16x8 va = *(const f16x8*)&Vtt[cur][mf*16 + lr][chs];
        #pragma unroll
        for (int qi=0;qi<4;qi++)
          ct[mf][qi] = __builtin_amdgcn_mfma_f32_16x16x32_f16(va, pb[qi], ct[mf][qi],0,0,0);
      }
    }
    cur ^= 1;
  }

  // merge per-lane l across the 16-lane group; publish stats
  #pragma unroll
  for (int qi=0;qi<4;qi++)
    #pragma unroll
    for (int j=0;j<4;j++) {
      float ls = l_[qi][j];
      #pragma unroll
      for (int d=1; d<16; d<<=1) ls += __shfl_xor(ls, d);
      float ilv = (ls > 0.f) ? 1.f/ls : 0.f;
      if (lr == 0) {
        ssc[wave][qi][lg*4+j] = ilv;
        float mgv = (mu[qi][j] <= NEGINF) ? 0.f : mu[qi][j];
        stats[(size_t)bh*S_ + qb + qi*16 + lg*4 + j] = make_float2(mgv, ilv);
      }
    }
  asm volatile("s_waitcnt lgkmcnt(0)" ::: "memory");
  __builtin_amdgcn_sched_barrier(0);
  float il[4];
  #pragma unroll
  for (int qi=0;qi<4;qi++) il[qi] = ssc[wave][qi][lr];

  // ct[mf][qi]: row dk = mf*16+lg*4+j, col q = qi*16+lr  ->  bounce to [q][dk]
  #pragma unroll
  for (int mf=0; mf<4; mf++)
    #pragma unroll
    for (int qi=0; qi<4; qi++) {
      f16x4 o;
      #pragma unroll
      for (int j=0;j<4;j++) o[j] = (f16)(ct[mf][qi][j] * il[qi]);
      *(f16x4*)&Pl[wave][qi*16 + lr][mf*16 + lg*4] = o;
    }
  __builtin_amdgcn_s_waitcnt(0);
  #pragma unroll
  for (int i=0;i<8;i++) {
    int idx = i*64 + lane;
    int row = idx >> 3, ch = idx & 7;
    f16x8 o = *(const f16x8*)&Pl[wave][row][ch*8];
    *(f16x8*)&ctx[(size_t)(b*S_ + qb + row)*D_ + h*64 + ch*8] = o;
  }
}

// ---------------- attn writer: one-shot 128x128 tile, gload_lds K staging, NT stores ----------------
__global__ __launch_bounds__(256, 2) void k_attnw(
    const f16* __restrict__ Qh, const f16* __restrict__ Kh,
    const uint32_t* __restrict__ amw, const uint32_t* __restrict__ kpw,
    const float2* __restrict__ stats, float* __restrict__ attnp) {
  __shared__ f16 Ks[128][64];   // linear; global already permuted+swizzled
  const int t = threadIdx.x, wave = t>>6, lane = t&63;
  const int lr = lane&15, lg = lane>>4;
  const int sh4 = 4*lr;
  const int ktb = blockIdx.x, qt = blockIdx.y, bh = blockIdx.z;
  const int b = bh >> 4, h = bh & 15;
  const int qb = qt*128, kb = ktb*128;
  const int srow = t>>3, sch = (t&7)*8, w8 = wave*8;
  const int ch0 = ((0|lg) ^ (lr&7))*8;
  const int ch1 = ((4|lg) ^ (lr&7))*8;

  #pragma unroll
  for (int q2=0; q2<4; q2++)
    gload16(&Kh[(size_t)(b*S_ + kb + q2*32 + srow)*D_ + h*64 + sch], &Ks[q2*32 + w8][0]);

  f16x8 qf[2][2];
  #pragma unroll
  for (int qi=0; qi<2; qi++)
    #pragma unroll
    for (int s=0; s<2; s++)
      qf[qi][s] = *(const f16x8*)&Qh[(size_t)(b*S_ + qb + wave*32 + qi*16 + lr)*D_ + h*64 + s*32 + lg*8];
  __syncthreads();   // only barrier; drains gload_lds

  f32x4 sf[2][8] = {};
  #pragma unroll
  for (int s=0;s<2;s++) {
    const int chs = s ? ch1 : ch0;
    #pragma unroll
    for (int f=0;f<8;f++) {
      f16x8 kf = *(const f16x8*)&Ks[f*16 + lr][chs];
      #pragma unroll
      for (int qi=0;qi<2;qi++)
        sf[qi][f] = __builtin_amdgcn_mfma_f32_16x16x32_f16(qf[qi][s], kf, sf[qi][f],0,0,0);
    }
  }

  uint32_t kw[4];
  #pragma unroll
  for (int i=0;i<4;i++) kw[i] = kpw[b*64 + ktb*4 + i];

  #pragma unroll
  for (int qi=0;qi<2;qi++)
    #pragma unroll
    for (int j=0;j<4;j++) {
      int qrow = qb + wave*32 + qi*16 + lg*4 + j;
      float2 st = stats[(size_t)bh*S_ + qrow];
      #pragma unroll
      for (int half=0; half<2; half++) {
        uint32_t a0 = amw[(size_t)qrow*64 + ktb*4 + half*2]     | kw[half*2];
        uint32_t a1 = amw[(size_t)qrow*64 + ktb*4 + half*2 + 1] | kw[half*2+1];
        int nb = (int)((((uint64_t)a1<<32) | a0) >> sh4) & 15;
        float x0 = (nb&1) ? NEGINF : sf[qi][half*4+0][j];
        float x1 = (nb&2) ? NEGINF : sf[qi][half*4+1][j];
        float x2 = (nb&4) ? NEGINF : sf[qi][half*4+2][j];
        float x3 = (nb&8) ? NEGINF : sf[qi][half*4+3][j];
        f32x4 ev;
        ev[0] = EXP2F(x0 - st.x) * st.y;
        ev[1] = EXP2F(x1 - st.x) * st.y;
        ev[2] = EXP2F(x2 - st.x) * st.y;
        ev[3] = EXP2F(x3 - st.x) * st.y;
        __builtin_nontemporal_store(ev,
            (f32x4*)&attnp[((size_t)bh*S_ + qrow)*S_ + kb + half*64 + sh4]);
      }
    }
}

// ---------------- launch ----------------
extern "C" void kernel_launch(void* const* d_in, const int* in_sizes, int n_in,
                              void* d_out, int out_size, void* d_ws, size_t ws_size,
                              hipStream_t stream) {
  const float* src = (const float*)d_in[0];
  const int*   am  = (const int*)d_in[1];
  const int*   kp  = (const int*)d_in[2];
  const float* Wq  = (const float*)d_in[3];
  const float* bq  = (const float*)d_in[4];
  const float* Wk  = (const float*)d_in[5];
  const float* bk  = (const float*)d_in[6];
  const float* Wv  = (const float*)d_in[7];
  const float* bv  = (const float*)d_in[8];
  const float* Wo  = (const float*)d_in[9];
  const float* bo  = (const float*)d_in[10];

  const size_t need = (size_t)M_*D_*2        // Xh
                    + (size_t)4*D_*D_*2      // Wth
                    + (size_t)4*M_*D_*2      // Qh,Kh,Vt,CT
                    + (size_t)S_*S_/8        // amw
                    + (size_t)B_*S_/8        // kpw
                    + (size_t)M_*8;          // stats
  if (ws_size < need) return;

  char* w = (char*)d_ws;
  f16* Xh  = (f16*)w;  w += (size_t)M_*D_*2;
  f16* Wth = (f16*)w;  w += (size_t)4*D_*D_*2;
  f16* Qh  = (f16*)w;  w += (size_t)M_*D_*2;
  f16* Kh  = (f16*)w;  w += (size_t)M_*D_*2;
  f16* Vt  = (f16*)w;  w += (size_t)M_*D_*2;
  f16* CT  = (f16*)w;  w += (size_t)M_*D_*2;
  uint32_t* amw = (uint32_t*)w; w += (size_t)S_*S_/8;
  uint32_t* kpw = (uint32_t*)w; w += (size_t)B_*S_/8;
  float2* stats = (float2*)w;

  float* outp  = (float*)d_out;
  float* attnp = outp + (size_t)M_*D_;

  k_prep<<<NB_SRC + NB_WT + NB_MSK, 256, 0, stream>>>(
      src, Xh, Wq, Wk, Wv, Wo, Wth, am, kp, amw, kpw);
  k_gemm_qkv<<<dim3(8,64,3), 256, 0, stream>>>(Xh, Wth, bq, bk, bv, Qh, Kh, Vt);
  k_flash<<<512, 256, 0, stream>>>(Qh, Kh, Vt, amw, kpw, stats, CT);
  k_gemm_o<<<dim3(8,64), 256, 0, stream>>>(CT, Wth + 3*(size_t)D_*D_, bo, outp);
  k_attnw<<<dim3(16,16,64), 256, 0, stream>>>(Qh, Kh, amw, kpw, stats, attnp);
}